// Round 2
// baseline (159.801 us; speedup 1.0000x reference)
//
#include <hip/hip_runtime.h>

// IndexedLinear: out[z, s*V:(s+1)*V] = coeff[s] * x[z, s*U:(s+1)*U] @ W[seg(z), s]
// S=8, U=V=32, C=32 segments, Z=65536. Memory-bound: ~134 MiB -> ~21us @ 6.3TB/s.
// R2 design:
//  - grid = (Z/256)*8 blocks; block = one (256-z tile, s) pair, 128 threads.
//  - X^T staged in LDS via register 4x4 transpose + ds_write_b128 (stride 260).
//  - W (coeff folded) staged in LDS (stride 36); reads are lane-broadcast.
//  - thread tile 8z x 8v: per-u 4x ds_read_b128 per 64 FMAs (1.0 B/FMA).
//  - counts prefix via wave shfl-scan + ballot; uniform-segment fast path.

constexpr int S = 8, U = 32, V = 32, C = 32, Z = 65536;
constexpr int BZ = 256;      // z rows per block
constexpr int NT = 128;      // threads per block (2 waves)
constexpr int ZS = BZ + 4;   // 260: X^T row stride (16B-aligned, breaks pow2)
constexpr int WS = 36;       // W row stride

typedef float f4 __attribute__((ext_vector_type(4)));

__global__ __launch_bounds__(NT) void IndexedLinear_kernel(
    const float* __restrict__ W_all,   // (C, S*U*V)
    const float* __restrict__ X,       // (Z, S*U)
    const int*   __restrict__ counts,  // (C,)
    const float* __restrict__ coeff,   // (S,)
    float*       __restrict__ out)     // (Z, S*V)
{
  const int tid = threadIdx.x;
  const int s   = blockIdx.x & 7;
  const int z0  = (blockIdx.x >> 3) * BZ;

  __shared__ float XT[U * ZS];   // 33280 B
  __shared__ float Wl[U * WS];   // 4608 B
  __shared__ int   pre[C];       // exclusive prefix of counts
  __shared__ int   sseg0, suni;

  // ---- issue X staging loads first (16 f4, independent, NT-hint) ----
  const int uq  = tid & 7;    // u quad
  const int zq4 = tid >> 3;   // 0..15
  f4 xv[4][4];
  {
    const float* xb = X + (size_t)(z0 + zq4 * 4) * (S * U) + s * U + uq * 4;
    #pragma unroll
    for (int r = 0; r < 4; ++r)
      #pragma unroll
      for (int i = 0; i < 4; ++i)
        xv[r][i] = __builtin_nontemporal_load(
            (const f4*)(xb + (size_t)(r * 64 + i) * (S * U)));
  }

  // ---- prologue: wave 0 scans counts, finds seg(z0) and uniformity ----
  if (tid < 64) {
    int c = (tid < C) ? counts[tid] : 0;
    int inc = c;
    #pragma unroll
    for (int d = 1; d < 32; d <<= 1) {
      int o = __shfl_up(inc, d, 64);
      if (tid >= d) inc += o;
    }
    const int exc = inc - c;                 // pre[tid]
    if (tid < C) pre[tid] = exc;
    const unsigned long long ma = __ballot(tid < C && exc <= z0);
    const unsigned long long mb = __ballot(tid < C && exc <= z0 + BZ - 1);
    if (tid == 0) {
      const int a = __popcll(ma) - 1;
      const int b = __popcll(mb) - 1;
      sseg0 = a;
      suni  = (a == b);
    }
  }
  __syncthreads();

  const int   seg0 = sseg0;
  const int   uni  = suni;
  const float cs   = coeff[s];

  // ---- stage W for seg0, coeff folded (harmless if !uni) ----
  {
    const float* wb = W_all + (size_t)seg0 * (S * U * V) + s * (U * V);
    #pragma unroll
    for (int k = 0; k < 2; ++k) {
      const int idx = tid + k * NT;          // 0..255 float4s
      f4 wv = *(const f4*)(wb + idx * 4);
      wv *= cs;
      *(f4*)&Wl[(idx >> 3) * WS + (idx & 7) * 4] = wv;
    }
  }

  // ---- register 4x4 transpose -> b128 LDS writes ----
  #pragma unroll
  for (int r = 0; r < 4; ++r) {
    #pragma unroll
    for (int j = 0; j < 4; ++j) {
      f4 t;
      t[0] = xv[r][0][j]; t[1] = xv[r][1][j];
      t[2] = xv[r][2][j]; t[3] = xv[r][3][j];
      *(f4*)&XT[(uq * 4 + j) * ZS + zq4 * 4 + r * 64] = t;
    }
  }
  __syncthreads();

  // ---- compute: thread tile 8z x 8v ----
  const int vg = tid & 3;    // 8 v's at vg*8
  const int zg = tid >> 2;   // 0..31, 8 z's at zg*8
  float acc[8][8] = {};

  if (uni) {
    #pragma unroll 8
    for (int u = 0; u < U; ++u) {
      const f4 w0 = *(const f4*)&Wl[u * WS + vg * 8];
      const f4 w1 = *(const f4*)&Wl[u * WS + vg * 8 + 4];
      const f4 xa = *(const f4*)&XT[u * ZS + zg * 8];
      const f4 xb = *(const f4*)&XT[u * ZS + zg * 8 + 4];
      #pragma unroll
      for (int i = 0; i < 4; ++i) {
        #pragma unroll
        for (int j = 0; j < 4; ++j) {
          acc[i][j]         += xa[i] * w0[j];
          acc[i][4 + j]     += xa[i] * w1[j];
          acc[4 + i][j]     += xb[i] * w0[j];
          acc[4 + i][4 + j] += xb[i] * w1[j];
        }
      }
    }
  } else {
    // general fallback: per-z segment lookup, W from global
    #pragma unroll 1
    for (int zi = 0; zi < 8; ++zi) {
      const int z = z0 + zg * 8 + zi;
      int sg = 0;
      #pragma unroll 1
      for (int i = 1; i < C; ++i) if (pre[i] <= z) sg = i;
      const float* wb2 = W_all + (size_t)sg * (S * U * V) + s * (U * V) + vg * 8;
      #pragma unroll 1
      for (int u = 0; u < U; ++u) {
        const float xs = XT[u * ZS + zg * 8 + zi];
        #pragma unroll
        for (int j = 0; j < 8; ++j) acc[zi][j] += xs * wb2[u * V + j];
      }
      #pragma unroll
      for (int j = 0; j < 8; ++j) acc[zi][j] *= cs;
    }
  }

  // ---- store: 2 f4 per z row (32 B contiguous per thread) ----
  float* ob = out + (size_t)(z0 + zg * 8) * (S * V) + s * V + vg * 8;
  #pragma unroll
  for (int zi = 0; zi < 8; ++zi) {
    f4 o0, o1;
    o0[0] = acc[zi][0]; o0[1] = acc[zi][1]; o0[2] = acc[zi][2]; o0[3] = acc[zi][3];
    o1[0] = acc[zi][4]; o1[1] = acc[zi][5]; o1[2] = acc[zi][6]; o1[3] = acc[zi][7];
    *(f4*)(ob + (size_t)zi * (S * V))     = o0;
    *(f4*)(ob + (size_t)zi * (S * V) + 4) = o1;
  }
}

extern "C" void kernel_launch(void* const* d_in, const int* in_sizes, int n_in,
                              void* d_out, int out_size, void* d_ws, size_t ws_size,
                              hipStream_t stream) {
  const float* input1       = (const float*)d_in[0];  // (C, S*U*V)
  const float* input2       = (const float*)d_in[1];  // (Z, S*U)
  const int*   counts       = (const int*)d_in[2];    // (C,)
  const float* coefficients = (const float*)d_in[3];  // (S,)
  float*       out          = (float*)d_out;          // (Z, S*V)

  const int grid = (Z / BZ) * S;  // 2048 blocks
  IndexedLinear_kernel<<<grid, NT, 0, stream>>>(input1, input2, counts,
                                                coefficients, out);
}

// Round 3
// 131.345 us; speedup vs baseline: 1.2166x; 1.2166x over previous
//
#include <hip/hip_runtime.h>

// IndexedLinear: out[z, s*V:(s+1)*V] = coeff[s] * x[z, s*U:(s+1)*U] @ W[seg(z), s]
// S=8, U=V=32, C=32 segments, Z=65536. Memory-bound: ~134 MiB -> ~21us @ 6.3TB/s.
// R3 design (fixes R2's write amplification + LDS bank conflicts):
//  - grid = (Z/256)*8 blocks; block = one (256-z tile, s) pair, NT=256 (4 waves).
//  - thread tile 8z x 4v, vg=tid&7: store instrs write FULL 128-B lines with
//    contiguous lanes (R2's strided 16-B stores caused 190MB vs 67MB writes).
//  - XT in LDS with 16-B pad every 32 z: pos(z)=z+((z>>5)<<2), row stride 292.
//    Compute reads: 8 distinct bank-quads x 8-lane broadcast -> conflict-free.
//    Transpose writes: 2-way max (free).
//  - W (coeff folded) LDS rows stride 36; reads conflict-free broadcast.
//  - nontemporal loads (X) and stores (out): both touched exactly once.

constexpr int S = 8, U = 32, V = 32, C = 32, Z = 65536;
constexpr int BZ  = 256;     // z rows per block
constexpr int NT  = 256;     // threads per block (4 waves)
constexpr int XTS = 292;     // XT row stride in floats (288 data + 4 pad)
constexpr int WS  = 36;      // W row stride
constexpr int SU  = S * U;   // 256
constexpr int SV  = S * V;   // 256

typedef float f4 __attribute__((ext_vector_type(4)));

__device__ __forceinline__ int zpos(int z) { return z + ((z >> 5) << 2); }

__global__ __launch_bounds__(NT) void IndexedLinear_kernel(
    const float* __restrict__ W_all,   // (C, S*U*V)
    const float* __restrict__ X,       // (Z, S*U)
    const int*   __restrict__ counts,  // (C,)
    const float* __restrict__ coeff,   // (S,)
    float*       __restrict__ out)     // (Z, S*V)
{
  const int tid = threadIdx.x;
  const int s   = blockIdx.x & 7;
  const int z0  = (blockIdx.x >> 3) * BZ;

  __shared__ float XT[U * XTS];  // 37376 B
  __shared__ float Wl[U * WS];   // 4608 B
  __shared__ int   pre[C];
  __shared__ int   sseg0, suni;

  // ---- issue X staging loads first (8 f4/thread, independent) ----
  const int uq = tid & 7;    // u quad: u = uq*4..+3
  const int zq = tid >> 3;   // 0..31
  f4 xv[2][4];
  {
    const float* xb = X + (size_t)z0 * SU + s * U + uq * 4;
    #pragma unroll
    for (int r = 0; r < 2; ++r)
      #pragma unroll
      for (int i = 0; i < 4; ++i)
        xv[r][i] = __builtin_nontemporal_load(
            (const f4*)(xb + (size_t)(zq * 4 + r * 128 + i) * SU));
  }

  // ---- wave 0: prefix-scan counts, segment of tile + uniformity ----
  if (tid < 64) {
    int c = (tid < C) ? counts[tid] : 0;
    int inc = c;
    #pragma unroll
    for (int d = 1; d < 32; d <<= 1) {
      int o = __shfl_up(inc, d, 64);
      if (tid >= d) inc += o;
    }
    const int exc = inc - c;
    if (tid < C) pre[tid] = exc;
    const unsigned long long ma = __ballot(tid < C && exc <= z0);
    const unsigned long long mb = __ballot(tid < C && exc <= z0 + BZ - 1);
    if (tid == 0) {
      const int a = __popcll(ma) - 1;
      const int b = __popcll(mb) - 1;
      sseg0 = a;
      suni  = (a == b);
    }
  }
  __syncthreads();

  const int   seg0 = sseg0;
  const int   uni  = suni;
  const float cs   = coeff[s];

  // ---- stage W for seg0, coeff folded (harmless if !uni) ----
  {
    const float* wb = W_all + (size_t)seg0 * (S * U * V) + s * (U * V);
    f4 wv = *(const f4*)(wb + tid * 4);          // 256 f4 = whole 32x32 tile
    wv *= cs;
    *(f4*)&Wl[(tid >> 3) * WS + (tid & 7) * 4] = wv;
  }

  // ---- register 4x4 transpose -> b128 LDS writes (2-way banks max) ----
  #pragma unroll
  for (int r = 0; r < 2; ++r) {
    const int zb_ = zq * 4 + r * 128;            // base z of this quad
    const int zp  = zpos(zb_);                   // contiguous quad in LDS
    #pragma unroll
    for (int j = 0; j < 4; ++j) {
      f4 t;
      t[0] = xv[r][0][j]; t[1] = xv[r][1][j];
      t[2] = xv[r][2][j]; t[3] = xv[r][3][j];
      *(f4*)&XT[(uq * 4 + j) * XTS + zp] = t;
    }
  }
  __syncthreads();

  // ---- compute: thread tile 8z x 4v ----
  const int vg   = tid & 7;    // v = vg*4..+3 (full 128-B line across 8 lanes)
  const int zg   = tid >> 3;   // 0..31, z = zg*8..+7
  const int zoff = zpos(zg * 8);
  float acc[8][4] = {};

  if (uni) {
    #pragma unroll 8
    for (int u = 0; u < U; ++u) {
      const f4 w  = *(const f4*)&Wl[u * WS + vg * 4];
      const f4 xa = *(const f4*)&XT[u * XTS + zoff];
      const f4 xb = *(const f4*)&XT[u * XTS + zoff + 4];
      #pragma unroll
      for (int i = 0; i < 4; ++i) {
        #pragma unroll
        for (int j = 0; j < 4; ++j) {
          acc[i][j]     += xa[i] * w[j];
          acc[4 + i][j] += xb[i] * w[j];
        }
      }
    }
  } else {
    // general fallback: per-z segment lookup, W from global
    #pragma unroll 1
    for (int zi = 0; zi < 8; ++zi) {
      const int z = z0 + zg * 8 + zi;
      int sg = 0;
      #pragma unroll 1
      for (int i = 1; i < C; ++i) if (pre[i] <= z) sg = i;
      const float* wb2 = W_all + (size_t)sg * (S * U * V) + s * (U * V) + vg * 4;
      #pragma unroll 1
      for (int u = 0; u < U; ++u) {
        const float xs = XT[u * XTS + zpos(zg * 8 + zi)];
        #pragma unroll
        for (int j = 0; j < 4; ++j) acc[zi][j] += xs * wb2[u * V + j];
      }
      #pragma unroll
      for (int j = 0; j < 4; ++j) acc[zi][j] *= cs;
    }
  }

  // ---- store: 1 f4 per z row; 8 lanes cover a full 128-B line ----
  float* ob = out + (size_t)(z0 + zg * 8) * SV + s * V + vg * 4;
  #pragma unroll
  for (int zi = 0; zi < 8; ++zi) {
    f4 o;
    o[0] = acc[zi][0]; o[1] = acc[zi][1]; o[2] = acc[zi][2]; o[3] = acc[zi][3];
    __builtin_nontemporal_store(o, (f4*)(ob + (size_t)zi * SV));
  }
}

extern "C" void kernel_launch(void* const* d_in, const int* in_sizes, int n_in,
                              void* d_out, int out_size, void* d_ws, size_t ws_size,
                              hipStream_t stream) {
  const float* input1       = (const float*)d_in[0];  // (C, S*U*V)
  const float* input2       = (const float*)d_in[1];  // (Z, S*U)
  const int*   counts       = (const int*)d_in[2];    // (C,)
  const float* coefficients = (const float*)d_in[3];  // (S,)
  float*       out          = (float*)d_out;          // (Z, S*V)

  const int grid = (Z / BZ) * S;  // 2048 blocks
  IndexedLinear_kernel<<<grid, NT, 0, stream>>>(input1, input2, counts,
                                                coefficients, out);
}